// Round 4
// baseline (267.863 us; speedup 1.0000x reference)
//
#include <hip/hip_runtime.h>

#define IMG_H 512
#define IMG_W 512
#define RH 16                        // output rows per wave-task
#define STRIPS (IMG_H / RH)          // 32
#define PLANE_N (IMG_H * IMG_W)

// f32-rounded Gaussian(sigma=1.5, k=3) weights, matching JAX's f32 computation
constexpr float W_E = 0.30780133f;
constexpr float W_C = 0.38439734f;
constexpr float C1v = 1e-4f;
constexpr float C2v = 9e-4f;

// One input row's horizontal 3-tap conv sums for this lane's 4 columns.
struct HRow { float h1[4], h2[4], h11[4], h22[4], h12[4]; };   // 20 VGPRs
// Raw pixel row: 4 cols of each image + the (lane0/lane63 only) edge pixel.
struct Raw { float4 a, b; float aE, bE; };                     // 10 VGPRs

__device__ __forceinline__ void load_row(const float* __restrict__ A,
                                         const float* __restrict__ B,
                                         int row, int col0, int ecol, Raw& r) {
    if ((unsigned)row < (unsigned)IMG_H) {          // wave-uniform
        const size_t off = (size_t)row * IMG_W;
        r.a = *(const float4*)(A + off + col0);
        r.b = *(const float4*)(B + off + col0);
        float ae = 0.f, be = 0.f;
        if (ecol >= 0) {                            // ≤2 active lanes
            ae = A[off + ecol];
            be = B[off + ecol];
        }
        r.aE = ae; r.bE = be;
    } else {                                        // rows -1 / 512 are zero pad
        r.a = make_float4(0.f, 0.f, 0.f, 0.f);
        r.b = make_float4(0.f, 0.f, 0.f, 0.f);
        r.aE = 0.f; r.bE = 0.f;
    }
}

// Horizontal 3-tap of {a, b, a2, b2, ab} for 4 cols; halo via intra-wave
// shuffle, with the wave-edge columns patched from the edge load.
__device__ __forceinline__ void compute_h(const Raw& r, int lane, HRow& H) {
    float aL = __shfl_up(r.a.w, 1);
    float bL = __shfl_up(r.b.w, 1);
    float aR = __shfl_down(r.a.x, 1);
    float bR = __shfl_down(r.b.x, 1);
    if (lane == 0)  { aL = r.aE; bL = r.bE; }
    if (lane == 63) { aR = r.aE; bR = r.bE; }
    const float av[6] = {aL, r.a.x, r.a.y, r.a.z, r.a.w, aR};
    const float bv[6] = {bL, r.b.x, r.b.y, r.b.z, r.b.w, bR};
#pragma unroll
    for (int c = 0; c < 4; ++c) {
        const float am = av[c], a0 = av[c + 1], ap = av[c + 2];
        const float bm = bv[c], b0 = bv[c + 1], bp = bv[c + 2];
        H.h1[c]  = fmaf(W_E, am + ap, W_C * a0);
        H.h2[c]  = fmaf(W_E, bm + bp, W_C * b0);
        H.h11[c] = fmaf(W_E, fmaf(am, am, ap * ap), W_C * (a0 * a0));
        H.h22[c] = fmaf(W_E, fmaf(bm, bm, bp * bp), W_C * (b0 * b0));
        H.h12[c] = fmaf(W_E, fmaf(am, bm, ap * bp), W_C * (a0 * b0));
    }
}

// Vertical 3-tap over window rows (P, Q, R) + SSIM formula; partial sum.
__device__ __forceinline__ float out_row(const HRow& P, const HRow& Q,
                                         const HRow& R) {
    float s = 0.f;
#pragma unroll
    for (int c = 0; c < 4; ++c) {
        const float m1  = fmaf(W_E, P.h1[c]  + R.h1[c],  W_C * Q.h1[c]);
        const float m2  = fmaf(W_E, P.h2[c]  + R.h2[c],  W_C * Q.h2[c]);
        const float e11 = fmaf(W_E, P.h11[c] + R.h11[c], W_C * Q.h11[c]);
        const float e22 = fmaf(W_E, P.h22[c] + R.h22[c], W_C * Q.h22[c]);
        const float e12 = fmaf(W_E, P.h12[c] + R.h12[c], W_C * Q.h12[c]);
        const float mu1s = m1 * m1, mu2s = m2 * m2, m12 = m1 * m2;
        const float s11 = e11 - mu1s, s22 = e22 - mu2s, s12 = e12 - m12;
        const float num = fmaf(2.f, m12, C1v) * fmaf(2.f, s12, C2v);
        const float den = (mu1s + mu2s + C1v) * (s11 + s22 + C2v);
        s = fmaf(num, __builtin_amdgcn_rcpf(den), s);   // ~1e-7 rel vs 2% thr
    }
    return s;
}

// Wave-task = (plane, 16-row strip, 256-col half). 4 independent waves/block,
// no LDS, no barriers, no atomics. waves_per_eu pinned to (4,4): VGPR budget
// is exactly 128 and the allocator has no incentive to spill for occupancy
// (rounds 2/3 spilled chasing the 6- and 8-waves/EU boundaries: VGPR=84,64).
__global__ __launch_bounds__(256)
__attribute__((amdgpu_waves_per_eu(4, 4)))
void ssim_main_kernel(const float* __restrict__ img1,
                      const float* __restrict__ img2,
                      float* __restrict__ wsum)
{
    const int t = threadIdx.x;
    const int lane = t & 63;
    const int task = blockIdx.x * 4 + (t >> 6);     // 0..6143
    const int half  = task & 1;
    const int strip = (task >> 1) & (STRIPS - 1);
    const int plane = task >> 6;                    // 96 planes
    const int y0 = strip * RH;
    const int col0 = half * 256 + (lane << 2);
    const float* __restrict__ A = img1 + (size_t)plane * PLANE_N;
    const float* __restrict__ B = img2 + (size_t)plane * PLANE_N;

    // edge column: lane0 needs col0-1, lane63 needs col0+4; -1 = none/border
    int ecol = -1;
    if (lane == 0 && col0 > 0) ecol = col0 - 1;
    if (lane == 63 && col0 + 4 < IMG_W) ecol = col0 + 4;

    HRow HA, HB, HC;
    Raw R0, R1;
    float tsum = 0.f;

    // STANZA k: prefetch next raw row into RL, build Hnew from RU,
    // then (if the window is primed) emit one output row. sched_barrier(0)
    // stops the machine scheduler from hoisting later stanzas' loads into
    // extra live temporaries (the round-2/3 pressure blow-up).
#define STANZA(Hm2, Hm1, Hnew, RU, RL, yload, doout)        \
    do {                                                    \
        load_row(A, B, (yload), col0, ecol, (RL));          \
        compute_h((RU), lane, (Hnew));                      \
        if (doout) tsum += out_row((Hm2), (Hm1), (Hnew));   \
        __builtin_amdgcn_sched_barrier(0);                  \
    } while (0)

    load_row(A, B, y0 - 1, col0, ecol, R0);
    STANZA(HA, HA, HA, R0, R1, y0,     false);      // k=0: row y0-1 -> HA
    STANZA(HA, HA, HB, R1, R0, y0 + 1, false);      // k=1: row y0   -> HB

#pragma unroll 1
    for (int g = 0; g < 2; ++g) {                   // k = 2..13
        const int yb = y0 + 2 + 6 * g;
        STANZA(HA, HB, HC, R0, R1, yb,     true);
        STANZA(HB, HC, HA, R1, R0, yb + 1, true);
        STANZA(HC, HA, HB, R0, R1, yb + 2, true);
        STANZA(HA, HB, HC, R1, R0, yb + 3, true);
        STANZA(HB, HC, HA, R0, R1, yb + 4, true);
        STANZA(HC, HA, HB, R1, R0, yb + 5, true);
    }
    STANZA(HA, HB, HC, R0, R1, y0 + 14, true);      // k=14
    STANZA(HB, HC, HA, R1, R0, y0 + 15, true);      // k=15
    STANZA(HC, HA, HB, R0, R1, y0 + 16, true);      // k=16
    STANZA(HA, HB, HC, R1, R0, -1,      true);      // k=17 (no next row)
#undef STANZA

#pragma unroll
    for (int off = 32; off; off >>= 1) tsum += __shfl_xor(tsum, off, 64);
    if (lane == 0) wsum[task] = tsum;   // every slot written every launch
}

// Single block reduces the 6144 per-wave partials (no init kernel needed).
__global__ __launch_bounds__(256) void ssim_fin_kernel(
    const float* __restrict__ wsum, float* __restrict__ out, int n)
{
    const int t = threadIdx.x;
    double s = 0.0;
    for (int i = t; i < n; i += 256) s += (double)wsum[i];
#pragma unroll
    for (int off = 32; off; off >>= 1) s += __shfl_xor(s, off, 64);
    __shared__ double wp[4];
    if ((t & 63) == 0) wp[t >> 6] = s;
    __syncthreads();
    if (t == 0) out[0] = 1.0f - (float)(wp[0] + wp[1] + wp[2] + wp[3]);
}

extern "C" void kernel_launch(void* const* d_in, const int* in_sizes, int n_in,
                              void* d_out, int out_size, void* d_ws, size_t ws_size,
                              hipStream_t stream) {
    const float* img1 = (const float*)d_in[0];
    const float* img2 = (const float*)d_in[1];
    float* out = (float*)d_out;
    float* wsum = (float*)d_ws;

    const int planes = in_sizes[0] / PLANE_N;       // 32*3 = 96
    const int tasks = planes * STRIPS * 2;          // 6144 waves
    const int blocks = tasks / 4;                   // 1536

    ssim_main_kernel<<<blocks, 256, 0, stream>>>(img1, img2, wsum);
    ssim_fin_kernel<<<1, 256, 0, stream>>>(wsum, out, tasks);
}

// Round 5
// 229.143 us; speedup vs baseline: 1.1690x; 1.1690x over previous
//
#include <hip/hip_runtime.h>

#define IMG_H 512
#define IMG_W 512
#define RH 16                        // output rows per wave-task
#define STRIPS (IMG_H / RH)          // 32
#define QWAVES 4                     // 4 column-quarters (128 cols each) per row
#define PLANE_N (IMG_H * IMG_W)

// f32-rounded Gaussian(sigma=1.5, k=3) weights, matching JAX's f32 computation
constexpr float W_E = 0.30780133f;
constexpr float W_C = 0.38439734f;
constexpr float C1v = 1e-4f;
constexpr float C2v = 9e-4f;

// One input row's horizontal 3-tap conv sums for this lane's 2 columns.
struct HRow { float h1[2], h2[2], h11[2], h22[2], h12[2]; };   // 10 VGPRs
// Raw pixel row: 2 cols of each image + the (lane0/lane63 only) edge pixel.
struct Raw { float2 a, b; float aE, bE; };                     // 6 VGPRs

__device__ __forceinline__ void load_row(const float* __restrict__ A,
                                         const float* __restrict__ B,
                                         int row, int col0, int ecol, Raw& r) {
    if ((unsigned)row < (unsigned)IMG_H) {          // wave-uniform
        const size_t off = (size_t)row * IMG_W;
        r.a = *(const float2*)(A + off + col0);
        r.b = *(const float2*)(B + off + col0);
        float ae = 0.f, be = 0.f;
        if (ecol >= 0) {                            // ≤2 active lanes
            ae = A[off + ecol];
            be = B[off + ecol];
        }
        r.aE = ae; r.bE = be;
    } else {                                        // rows -1 / 512 are zero pad
        r.a = make_float2(0.f, 0.f);
        r.b = make_float2(0.f, 0.f);
        r.aE = 0.f; r.bE = 0.f;
    }
}

// Horizontal 3-tap of {a, b, a2, b2, ab} for 2 cols; halo via intra-wave
// shuffle, with the wave-edge columns patched from the edge load.
__device__ __forceinline__ void compute_h(const Raw& r, int lane, HRow& H) {
    float aL = __shfl_up(r.a.y, 1);
    float bL = __shfl_up(r.b.y, 1);
    float aR = __shfl_down(r.a.x, 1);
    float bR = __shfl_down(r.b.x, 1);
    if (lane == 0)  { aL = r.aE; bL = r.bE; }
    if (lane == 63) { aR = r.aE; bR = r.bE; }
    const float av[4] = {aL, r.a.x, r.a.y, aR};
    const float bv[4] = {bL, r.b.x, r.b.y, bR};
#pragma unroll
    for (int c = 0; c < 2; ++c) {
        const float am = av[c], a0 = av[c + 1], ap = av[c + 2];
        const float bm = bv[c], b0 = bv[c + 1], bp = bv[c + 2];
        H.h1[c]  = fmaf(W_E, am + ap, W_C * a0);
        H.h2[c]  = fmaf(W_E, bm + bp, W_C * b0);
        H.h11[c] = fmaf(W_E, fmaf(am, am, ap * ap), W_C * (a0 * a0));
        H.h22[c] = fmaf(W_E, fmaf(bm, bm, bp * bp), W_C * (b0 * b0));
        H.h12[c] = fmaf(W_E, fmaf(am, bm, ap * bp), W_C * (a0 * b0));
    }
}

// Vertical 3-tap over window rows (P, Q, R) + SSIM formula; partial sum.
__device__ __forceinline__ float out_row(const HRow& P, const HRow& Q,
                                         const HRow& R) {
    float s = 0.f;
#pragma unroll
    for (int c = 0; c < 2; ++c) {
        const float m1  = fmaf(W_E, P.h1[c]  + R.h1[c],  W_C * Q.h1[c]);
        const float m2  = fmaf(W_E, P.h2[c]  + R.h2[c],  W_C * Q.h2[c]);
        const float e11 = fmaf(W_E, P.h11[c] + R.h11[c], W_C * Q.h11[c]);
        const float e22 = fmaf(W_E, P.h22[c] + R.h22[c], W_C * Q.h22[c]);
        const float e12 = fmaf(W_E, P.h12[c] + R.h12[c], W_C * Q.h12[c]);
        const float mu1s = m1 * m1, mu2s = m2 * m2, m12 = m1 * m2;
        const float s11 = e11 - mu1s, s22 = e22 - mu2s, s12 = e12 - m12;
        const float num = fmaf(2.f, m12, C1v) * fmaf(2.f, s12, C2v);
        const float den = (mu1s + mu2s + C1v) * (s11 + s22 + C2v);
        s = fmaf(num, __builtin_amdgcn_rcpf(den), s);   // ~1e-7 rel vs 2% thr
    }
    return s;
}

// Wave-task = (plane, 16-row strip, 128-col quarter). 4 independent waves per
// block, no LDS, no barriers, no atomics. 2 cols/lane keeps peak live state
// ~57 VGPRs — inside the 64-reg/8-waves-per-EU budget the allocator insists
// on (rounds 2-4: demand ~95 vs budget 64 => 88-315 MB scratch spill traffic).
__global__ __launch_bounds__(256)
void ssim_main_kernel(const float* __restrict__ img1,
                      const float* __restrict__ img2,
                      float* __restrict__ wsum)
{
    const int t = threadIdx.x;
    const int lane = t & 63;
    const int task = blockIdx.x * 4 + (t >> 6);     // 0..12287
    const int quar  = task & (QWAVES - 1);
    const int strip = (task >> 2) & (STRIPS - 1);
    const int plane = task >> 7;                    // 96 planes
    const int y0 = strip * RH;
    const int col0 = quar * 128 + (lane << 1);
    const float* __restrict__ A = img1 + (size_t)plane * PLANE_N;
    const float* __restrict__ B = img2 + (size_t)plane * PLANE_N;

    // edge column: lane0 needs col0-1, lane63 needs col0+2; -1 = none/border
    int ecol = -1;
    if (lane == 0 && col0 > 0) ecol = col0 - 1;
    if (lane == 63 && col0 + 2 < IMG_W) ecol = col0 + 2;

    HRow HA, HB, HC;
    Raw R0, R1;
    float tsum = 0.f;

    // STANZA k: prefetch next raw row into RL, build Hnew from RU,
    // then (if the window is primed) emit one output row. sched_barrier(0)
    // keeps the scheduler from hoisting later stanzas' loads into extra
    // simultaneously-live temporaries (pressure insurance).
#define STANZA(Hm2, Hm1, Hnew, RU, RL, yload, doout)        \
    do {                                                    \
        load_row(A, B, (yload), col0, ecol, (RL));          \
        compute_h((RU), lane, (Hnew));                      \
        if (doout) tsum += out_row((Hm2), (Hm1), (Hnew));   \
        __builtin_amdgcn_sched_barrier(0);                  \
    } while (0)

    load_row(A, B, y0 - 1, col0, ecol, R0);
    STANZA(HA, HA, HA, R0, R1, y0,     false);      // k=0: row y0-1 -> HA
    STANZA(HA, HA, HB, R1, R0, y0 + 1, false);      // k=1: row y0   -> HB

#pragma unroll 1
    for (int g = 0; g < 2; ++g) {                   // k = 2..13
        const int yb = y0 + 2 + 6 * g;
        STANZA(HA, HB, HC, R0, R1, yb,     true);
        STANZA(HB, HC, HA, R1, R0, yb + 1, true);
        STANZA(HC, HA, HB, R0, R1, yb + 2, true);
        STANZA(HA, HB, HC, R1, R0, yb + 3, true);
        STANZA(HB, HC, HA, R0, R1, yb + 4, true);
        STANZA(HC, HA, HB, R1, R0, yb + 5, true);
    }
    STANZA(HA, HB, HC, R0, R1, y0 + 14, true);      // k=14
    STANZA(HB, HC, HA, R1, R0, y0 + 15, true);      // k=15
    STANZA(HC, HA, HB, R0, R1, y0 + 16, true);      // k=16
    STANZA(HA, HB, HC, R1, R0, -1,      true);      // k=17 (no next row)
#undef STANZA

#pragma unroll
    for (int off = 32; off; off >>= 1) tsum += __shfl_xor(tsum, off, 64);
    if (lane == 0) wsum[task] = tsum;   // every slot written every launch
}

// Single block reduces the 12288 per-wave partials (all in L2 by launch time).
__global__ __launch_bounds__(256) void ssim_fin_kernel(
    const float* __restrict__ wsum, float* __restrict__ out, int n)
{
    const int t = threadIdx.x;
    double s = 0.0;
    for (int i = t; i < n; i += 256) s += (double)wsum[i];
#pragma unroll
    for (int off = 32; off; off >>= 1) s += __shfl_xor(s, off, 64);
    __shared__ double wp[4];
    if ((t & 63) == 0) wp[t >> 6] = s;
    __syncthreads();
    if (t == 0) out[0] = 1.0f - (float)(wp[0] + wp[1] + wp[2] + wp[3]);
}

extern "C" void kernel_launch(void* const* d_in, const int* in_sizes, int n_in,
                              void* d_out, int out_size, void* d_ws, size_t ws_size,
                              hipStream_t stream) {
    const float* img1 = (const float*)d_in[0];
    const float* img2 = (const float*)d_in[1];
    float* out = (float*)d_out;
    float* wsum = (float*)d_ws;

    const int planes = in_sizes[0] / PLANE_N;       // 32*3 = 96
    const int tasks = planes * STRIPS * QWAVES;     // 12288 waves
    const int blocks = tasks / 4;                   // 3072

    ssim_main_kernel<<<blocks, 256, 0, stream>>>(img1, img2, wsum);
    ssim_fin_kernel<<<1, 256, 0, stream>>>(wsum, out, tasks);
}